// Round 1
// baseline (1033.461 us; speedup 1.0000x reference)
//
#include <hip/hip_runtime.h>
#include <hip/hip_bf16.h>

#define N_NODES   500000
#define HIDDEN    256
#define NCLASS    104
#define NGRAPH    2048
#define NCHUNK    15625      // N_NODES / 32
#define CPAD      112        // classes padded to 7*16

typedef __attribute__((ext_vector_type(8))) __bf16 bf16x8;
typedef __attribute__((ext_vector_type(8))) unsigned short ushort8;
typedef __attribute__((ext_vector_type(4))) float floatx4;

__device__ __forceinline__ unsigned short f2bf(float f) {
    unsigned u = __float_as_uint(f);
    u += 0x7fffu + ((u >> 16) & 1u);     // round-to-nearest-even
    return (unsigned short)(u >> 16);
}

// ---------------------------------------------------------------------------
// Kernel 0: build bf16 transposed weight buffers in workspace.
//   WgT: [CPAD][512]  (cols 104..111 zero)
//   WtT: [CPAD][256]
// ---------------------------------------------------------------------------
__global__ void prep_kernel(const float* __restrict__ Wg, const float* __restrict__ Wt,
                            unsigned short* __restrict__ WgT, unsigned short* __restrict__ WtT) {
    int id = blockIdx.x * 256 + threadIdx.x;
    if (id < CPAD * 512) {
        int c = id >> 9, k = id & 511;
        float v = (c < NCLASS) ? Wg[k * NCLASS + c] : 0.f;
        WgT[id] = f2bf(v);
    } else {
        int id2 = id - CPAD * 512;   // < CPAD*256
        int c = id2 >> 8, k = id2 & 255;
        float v = (c < NCLASS) ? Wt[k * NCLASS + c] : 0.f;
        WtT[id2] = f2bf(v);
    }
}

// ---------------------------------------------------------------------------
// Kernel 1: gated nodewise readout + segment-sum scatter.
// ---------------------------------------------------------------------------
__device__ __forceinline__ void load_chunk(const float* __restrict__ init_s,
                                           const float* __restrict__ fin_s,
                                           int chunk, int w, int lane, float4 (&pre)[4][2]) {
    const int nb = chunk * 32;
#pragma unroll
    for (int p = 0; p < 4; ++p) {
        const int node = nb + p * 8 + w;
        const float* src = (lane < 32)
            ? (init_s + (size_t)node * HIDDEN + lane * 8)
            : (fin_s  + (size_t)node * HIDDEN + (lane - 32) * 8);
        pre[p][0] = *(const float4*)(src);
        pre[p][1] = *(const float4*)(src + 4);
    }
}

__global__ __launch_bounds__(512, 2)
void node_kernel(const float* __restrict__ init_s, const float* __restrict__ fin_s,
                 const int* __restrict__ gl, const float* __restrict__ bg,
                 const float* __restrict__ bt,
                 const unsigned short* __restrict__ WgT,   // [CPAD][512] bf16
                 const unsigned short* __restrict__ WtT,   // [CPAD][256] bf16
                 float* __restrict__ readout)              // [NGRAPH][NCLASS]
{
    __shared__ unsigned short Atile[2][32 * 512];          // 64 KiB, double-buffered

    const int tid  = threadIdx.x;
    const int lane = tid & 63;
    const int w    = tid >> 6;            // wave 0..7
    const int l15  = lane & 15;
    const int quad = lane >> 4;
    const int col  = w * 16 + l15;        // output class column (waves 0..6)

    // ---- persistent B fragments (weights) in registers ----
    bf16x8 Bg[16], Bt[8];
    float bgv = 0.f, btv = 0.f;
    if (w < 7) {
        const int cc = (col < NCLASS) ? col : (NCLASS - 1);
        bgv = bg[cc]; btv = bt[cc];
        const unsigned short* wg = WgT + col * 512 + quad * 8;
#pragma unroll
        for (int s = 0; s < 16; ++s) Bg[s] = *(const bf16x8*)(wg + s * 32);
        const unsigned short* wt = WtT + col * 256 + quad * 8;
#pragma unroll
        for (int s = 0; s < 8; ++s)  Bt[s] = *(const bf16x8*)(wt + s * 32);
    }

    const int G = gridDim.x;
    int c = blockIdx.x;
    float4 pre[4][2];
    if (c < NCHUNK) load_chunk(init_s, fin_s, c, w, lane, pre);

    int buf = 0;
    for (; c < NCHUNK; c += G) {
        // ---- convert + stage current chunk into LDS[buf] ----
#pragma unroll
        for (int p = 0; p < 4; ++p) {
            const int r  = p * 8 + w;
            const int kp = (lane * 8) ^ ((r & 7) * 8);     // XOR swizzle, keeps 16B align
            ushort8 t;
            t[0] = f2bf(pre[p][0].x); t[1] = f2bf(pre[p][0].y);
            t[2] = f2bf(pre[p][0].z); t[3] = f2bf(pre[p][0].w);
            t[4] = f2bf(pre[p][1].x); t[5] = f2bf(pre[p][1].y);
            t[6] = f2bf(pre[p][1].z); t[7] = f2bf(pre[p][1].w);
            *reinterpret_cast<ushort8*>(&Atile[buf][r * 512 + kp]) = t;
        }
        // ---- prefetch next chunk into registers (stays in flight across barrier) ----
        const int nxt = c + G;
        if (nxt < NCHUNK) load_chunk(init_s, fin_s, nxt, w, lane, pre);

        __syncthreads();

        if (w < 7) {
            floatx4 accg0 = {0.f,0.f,0.f,0.f}, accg1 = {0.f,0.f,0.f,0.f};
            floatx4 acct0 = {0.f,0.f,0.f,0.f}, acct1 = {0.f,0.f,0.f,0.f};
            const unsigned short* Ab = &Atile[buf][0];
#pragma unroll
            for (int s = 0; s < 16; ++s) {
                const int kk = s * 32 + quad * 8;
                const int r0 = l15,      kp0 = kk ^ ((r0 & 7) * 8);
                const int r1 = 16 + l15, kp1 = kk ^ ((r1 & 7) * 8);
                bf16x8 a0 = *reinterpret_cast<const bf16x8*>(Ab + r0 * 512 + kp0);
                bf16x8 a1 = *reinterpret_cast<const bf16x8*>(Ab + r1 * 512 + kp1);
                accg0 = __builtin_amdgcn_mfma_f32_16x16x32_bf16(a0, Bg[s], accg0, 0, 0, 0);
                accg1 = __builtin_amdgcn_mfma_f32_16x16x32_bf16(a1, Bg[s], accg1, 0, 0, 0);
                if (s >= 8) {     // k in [256,512) -> final states: also feed transform
                    acct0 = __builtin_amdgcn_mfma_f32_16x16x32_bf16(a0, Bt[s - 8], acct0, 0, 0, 0);
                    acct1 = __builtin_amdgcn_mfma_f32_16x16x32_bf16(a1, Bt[s - 8], acct1, 0, 0, 0);
                }
            }
            // ---- epilogue: sigmoid gate, scale, segment-sum scatter ----
#pragma unroll
            for (int rc = 0; rc < 2; ++rc) {
                const floatx4 ag = rc ? accg1 : accg0;
                const floatx4 at = rc ? acct1 : acct0;
                const int nb = c * 32 + rc * 16;
                float vals[4];
#pragma unroll
                for (int j = 0; j < 4; ++j) {
                    const float sg = 1.f / (1.f + __expf(-(ag[j] + bgv)));
                    vals[j] = sg * (at[j] + btv);
                }
                const int gfirst = gl[nb];
                const int glast  = gl[nb + 15];
                if (gfirst == glast) {      // sorted -> whole 16-row tile is one graph
                    float v = vals[0] + vals[1] + vals[2] + vals[3];
                    v += __shfl_xor(v, 16, 64);
                    v += __shfl_xor(v, 32, 64);
                    if (quad == 0 && col < NCLASS)
                        atomicAdd(&readout[gfirst * NCLASS + col], v);
                } else {                    // boundary chunk (~6.5%): per-row atomics
#pragma unroll
                    for (int j = 0; j < 4; ++j) {
                        const int node = nb + quad * 4 + j;
                        const int g = gl[node];
                        if (col < NCLASS)
                            atomicAdd(&readout[g * NCLASS + col], vals[j]);
                    }
                }
            }
        }
        buf ^= 1;
    }
}

// ---------------------------------------------------------------------------
// Kernel 2: BatchNorm (eval) + feed_forward MLP. 8 graphs per block.
// ---------------------------------------------------------------------------
__global__ __launch_bounds__(128)
void mlp_kernel(const float* __restrict__ readout, const float* __restrict__ aux,
                const float* __restrict__ gamma, const float* __restrict__ beta,
                const float* __restrict__ mean, const float* __restrict__ var,
                const float* __restrict__ W1, const float* __restrict__ b1,
                const float* __restrict__ W2, const float* __restrict__ b2,
                float* __restrict__ out)
{
    __shared__ float xs[8][112];
    __shared__ float hs[8][128];
    const int g0 = blockIdx.x * 8;
    const int tid = threadIdx.x;

    for (int v = tid; v < 8 * 106; v += 128) {
        const int r = v / 106, i = v - r * 106;
        const float raw = (i < NCLASS) ? readout[(g0 + r) * NCLASS + i]
                                       : aux[(g0 + r) * 2 + (i - NCLASS)];
        xs[r][i] = (raw - mean[i]) * rsqrtf(var[i] + 1e-5f) * gamma[i] + beta[i];
    }
    __syncthreads();
    {
        const int j = tid;   // 0..127
        float acc[8];
#pragma unroll
        for (int r = 0; r < 8; ++r) acc[r] = b1[j];
        for (int i = 0; i < 106; ++i) {
            const float ww = W1[i * 128 + j];
#pragma unroll
            for (int r = 0; r < 8; ++r) acc[r] += xs[r][i] * ww;
        }
#pragma unroll
        for (int r = 0; r < 8; ++r) hs[r][j] = fmaxf(acc[r], 0.f);
    }
    __syncthreads();
    if (tid < NCLASS) {
        float acc[8];
#pragma unroll
        for (int r = 0; r < 8; ++r) acc[r] = b2[tid];
        for (int j = 0; j < 128; ++j) {
            const float ww = W2[j * NCLASS + tid];
#pragma unroll
            for (int r = 0; r < 8; ++r) acc[r] += hs[r][j] * ww;
        }
#pragma unroll
        for (int r = 0; r < 8; ++r) out[(g0 + r) * NCLASS + tid] = acc[r];
    }
}

// ---------------------------------------------------------------------------
extern "C" void kernel_launch(void* const* d_in, const int* in_sizes, int n_in,
                              void* d_out, int out_size, void* d_ws, size_t ws_size,
                              hipStream_t stream) {
    const float* init_s = (const float*)d_in[0];
    const float* fin_s  = (const float*)d_in[1];
    const float* aux    = (const float*)d_in[2];
    const int*   gl     = (const int*)d_in[3];
    // d_in[4] = num_graphs (2048, hardcoded)
    const float* Wg = (const float*)d_in[5];
    const float* bg = (const float*)d_in[6];
    const float* Wt = (const float*)d_in[7];
    const float* bt = (const float*)d_in[8];
    const float* bn_gamma = (const float*)d_in[9];
    const float* bn_beta  = (const float*)d_in[10];
    const float* bn_mean  = (const float*)d_in[11];
    const float* bn_var   = (const float*)d_in[12];
    const float* W1 = (const float*)d_in[13];
    const float* b1 = (const float*)d_in[14];
    const float* W2 = (const float*)d_in[15];
    const float* b2 = (const float*)d_in[16];
    float* out = (float*)d_out;

    char* ws = (char*)d_ws;
    float* readout      = (float*)ws;                               // 2048*104*4 = 851,968 B
    unsigned short* WgT = (unsigned short*)(ws + 851968);           // 112*512*2 = 114,688 B
    unsigned short* WtT = (unsigned short*)(ws + 851968 + 114688);  // 112*256*2 =  57,344 B

    hipMemsetAsync(readout, 0, NGRAPH * NCLASS * sizeof(float), stream);
    prep_kernel<<<336, 256, 0, stream>>>(Wg, Wt, WgT, WtT);
    node_kernel<<<256, 512, 0, stream>>>(init_s, fin_s, gl, bg, bt, WgT, WtT, readout);
    mlp_kernel<<<NGRAPH / 8, 128, 0, stream>>>(readout, aux, bn_gamma, bn_beta,
                                               bn_mean, bn_var, W1, b1, W2, b2, out);
}